// Round 9
// baseline (249.564 us; speedup 1.0000x reference)
//
#include <hip/hip_runtime.h>
#include <hip/hip_bf16.h>

typedef __attribute__((ext_vector_type(8))) short bf16x8;
typedef __attribute__((ext_vector_type(4))) float f32x4;
typedef __attribute__((ext_vector_type(16))) float f32x16;
typedef __attribute__((ext_vector_type(4))) unsigned int u32x4;

__device__ inline unsigned short f2bf(float f) {
    unsigned int u = __builtin_bit_cast(unsigned int, f);
    u += 0x7FFFu + ((u >> 16) & 1u);
    return (unsigned short)(u >> 16);
}
__device__ inline float bf2f(unsigned short h) {
    unsigned int u = ((unsigned int)h) << 16;
    return __builtin_bit_cast(float, u);
}
__device__ inline unsigned int pkbf(float a, float b) {
    return (unsigned int)f2bf(a) | ((unsigned int)f2bf(b) << 16);
}
// hardware packed f32->bf16 (RNE), gfx950: no builtin -> inline asm
__device__ inline unsigned int cvtpk(float lo, float hi) {
    unsigned int r;
    asm("v_cvt_pk_bf16_f32 %0, %1, %2" : "=v"(r) : "v"(lo), "v"(hi));
    return r;
}

// ---------------- conversion kernels ----------------

__global__ void k_conv_x(const float* __restrict__ in, unsigned short* __restrict__ out, int n4) {
    int i = blockIdx.x * blockDim.x + threadIdx.x;
    if (i >= n4) return;
    float4 v = ((const float4*)in)[i];
    uint2 o;
    o.x = (unsigned)f2bf(v.x) | ((unsigned)f2bf(v.y) << 16);
    o.y = (unsigned)f2bf(v.z) | ((unsigned)f2bf(v.w) << 16);
    ((uint2*)out)[i] = o;
}

// W fp32 [2048][2048] -> W^T bf16 [2048][2048]; z selects weight
__global__ void k_wT(const float* __restrict__ w0, const float* __restrict__ w1,
                     const float* __restrict__ w2, const float* __restrict__ w3,
                     unsigned short* __restrict__ out) {
    __shared__ float tile[32][33];
    int z = blockIdx.z;
    const float* W = (z == 0) ? w0 : (z == 1) ? w1 : (z == 2) ? w2 : w3;
    unsigned short* O = out + (size_t)z * 2048 * 2048;
    int n0 = blockIdx.x * 32, k0 = blockIdx.y * 32;
    int tx = threadIdx.x & 31, ty = threadIdx.x >> 5;
#pragma unroll
    for (int j = 0; j < 4; ++j)
        tile[ty + j * 8][tx] = W[(size_t)(k0 + ty + j * 8) * 2048 + n0 + tx];
    __syncthreads();
#pragma unroll
    for (int j = 0; j < 4; ++j)
        O[(size_t)(n0 + ty + j * 8) * 2048 + k0 + tx] = f2bf(tile[tx][ty + j * 8]);
}

// interleaved (cos, sin) table: csT[s*64 + i] = {cos(s*invfreq_i), sin(...)}
__global__ void k_cs_table(float2* __restrict__ csT) {
    int t = blockIdx.x * 256 + threadIdx.x;  // 2048*64
    int s = t >> 6, i = t & 63;
    float inv = __expf(-((float)i / 64.0f) * 9.210340371976184f); // 10000^(-i/64)
    float ang = (float)s * inv;
    csT[t] = make_float2(cosf(ang), sinf(ang));
}

// ---------------- GEMM: C[M][N] = A[M][K] * Bt[N][K]^T ----------------
// R3 hot loop (128x128 tile, 4 waves, 2-barrier, gload_lds w16, granule-XOR).
// Wave N-columns remapped to wn*32 + (ni&1)*16 + (ni>>1)*64 so each lane holds
// RoPE pairs (d, d+64) in (ni, ni+2).
// launch_bounds(256,6): cap VGPR at 85 so 5 blocks/CU stay resident (R8 fix:
// the fused epilogue pushed VGPR to 100 -> 4 blocks -> -20% MfmaUtil).
// sched_barrier(0) fences keep epilogue loads out of the hot loop.
template <int OUT_MODE>
__global__ __launch_bounds__(256, 6) void gemm_bt(const unsigned short* __restrict__ A,
                                                  const unsigned short* __restrict__ Bt,
                                                  void* __restrict__ outp,
                                                  unsigned short* __restrict__ vtp,
                                                  const float2* __restrict__ csT,
                                                  int M, int N, int K) {
    __shared__ __align__(16) unsigned short As[128 * 64];
    __shared__ __align__(16) unsigned short Bs[128 * 64];
    const int tid = threadIdx.x, w = tid >> 6, l = tid & 63;
    const int m0 = blockIdx.y * 128, n0 = blockIdx.x * 128;
    const int wm = w >> 1, wn = w & 1;
    const int l15 = l & 15, lq = l >> 4;
    f32x4 acc[4][4] = {};
    const int lr = l >> 3, lg = l & 7;
    const int srcg = lg ^ lr;  // source granule (row&7 == lr since r0 % 8 == 0)

    const int nkt = K >> 6;
    for (int kt = 0; kt < nkt; ++kt) {
        if (kt) __syncthreads();
#pragma unroll
        for (int i = 0; i < 4; ++i) {
            int r0 = (w * 4 + i) * 8;
            int row = r0 + lr;
            const unsigned short* sa = A + (size_t)(m0 + row) * K + kt * 64 + srcg * 8;
            __builtin_amdgcn_global_load_lds((const void*)sa, (void*)&As[(w * 4 + i) * 512], 16, 0, 0);
            const unsigned short* sb = Bt + (size_t)(n0 + row) * K + kt * 64 + srcg * 8;
            __builtin_amdgcn_global_load_lds((const void*)sb, (void*)&Bs[(w * 4 + i) * 512], 16, 0, 0);
        }
        __syncthreads();
#pragma unroll
        for (int kb = 0; kb < 2; ++kb) {
            bf16x8 af[4], bfr[4];
#pragma unroll
            for (int mi = 0; mi < 4; ++mi) {
                int row = wm * 64 + mi * 16 + l15;
                int g = (kb * 4 + lq) ^ (row & 7);
                af[mi] = *(const bf16x8*)&As[row * 64 + g * 8];
            }
#pragma unroll
            for (int ni = 0; ni < 4; ++ni) {
                int row = wn * 32 + (ni & 1) * 16 + (ni >> 1) * 64 + l15;  // colmap
                int g = (kb * 4 + lq) ^ (row & 7);
                bfr[ni] = *(const bf16x8*)&Bs[row * 64 + g * 8];
            }
#pragma unroll
            for (int mi = 0; mi < 4; ++mi)
#pragma unroll
                for (int ni = 0; ni < 4; ++ni)
                    acc[mi][ni] = __builtin_amdgcn_mfma_f32_16x16x32_bf16(af[mi], bfr[ni],
                                                                          acc[mi][ni], 0, 0, 0);
        }
    }
    __builtin_amdgcn_sched_barrier(0);  // keep epilogue out of the K-loop

    if constexpr (OUT_MODE == 0) {
        const int tsel = n0 >> 11, nloc = n0 & 2047;
        if (tsel < 2) {
            // Q/K: RoPE in-register (pairs in ni / ni+2), Q pre-scaled for exp2 softmax
            unsigned short* op = (unsigned short*)outp + (size_t)tsel * M * 2048;
            const float scale = (tsel == 0) ? 0.12751742f : 1.0f;  // log2e/sqrt(128)
#pragma unroll
            for (int mi = 0; mi < 4; ++mi) {
                __builtin_amdgcn_sched_barrier(0);  // limit load batching per mi
#pragma unroll
                for (int ni = 0; ni < 2; ++ni) {
                    const int i = wn * 32 + ni * 16 + l15;  // d in [0,64)
#pragma unroll
                    for (int r = 0; r < 4; ++r) {
                        int row = m0 + wm * 64 + mi * 16 + lq * 4 + r;
                        int sp = row & 2047;
                        float2 cs = csT[sp * 64 + i];
                        float a = acc[mi][ni][r], bb = acc[mi][ni + 2][r];
                        op[(size_t)row * 2048 + nloc + i]      = f2bf((a * cs.x - bb * cs.y) * scale);
                        op[(size_t)row * 2048 + nloc + i + 64] = f2bf((bb * cs.x + a * cs.y) * scale);
                    }
                }
            }
        } else {
            // V: fused transpose -> vT[(b*16+h)*128 + d][s], packed 8B along s
            const int h = nloc >> 7;
            const int bsel = m0 >> 11;
            const int sp0 = (m0 & 2047) + wm * 64;
#pragma unroll
            for (int mi = 0; mi < 4; ++mi) {
                __builtin_amdgcn_sched_barrier(0);
#pragma unroll
                for (int ni = 0; ni < 4; ++ni) {
                    int d = wn * 32 + (ni & 1) * 16 + (ni >> 1) * 64 + l15;
                    uint2 pv;
                    pv.x = cvtpk(acc[mi][ni][0], acc[mi][ni][1]);
                    pv.y = cvtpk(acc[mi][ni][2], acc[mi][ni][3]);
                    *(uint2*)&vtp[((size_t)((bsel * 16 + h) * 128 + d)) * 2048 + sp0 + mi * 16 + lq * 4] = pv;
                }
            }
        }
    } else {
        float* op = (float*)outp;
#pragma unroll
        for (int mi = 0; mi < 4; ++mi) {
            __builtin_amdgcn_sched_barrier(0);
#pragma unroll
            for (int ni = 0; ni < 4; ++ni)
#pragma unroll
                for (int r = 0; r < 4; ++r) {
                    int row = m0 + wm * 64 + mi * 16 + lq * 4 + r;
                    int col = n0 + wn * 32 + (ni & 1) * 16 + (ni >> 1) * 64 + l15;
                    op[(size_t)row * 2048 + col] = acc[mi][ni][r];
                }
        }
    }
}

// ---------------- flash attention (causal), v3c: swapped-QK 32x32 ----------------
// 4 waves x 32 q-rows = 128-row Q tile, paired (15-pr, pr). KV tile 64, dbuf LDS
// (64KB -> 2 blocks/CU). Softmax fully in-lane; P repack via hw cvt_pk +
// 2x shfl_xor(32) per k-step. Q pre-scaled by log2e/sqrt(128) -> exp2 domain.
__global__ __launch_bounds__(256, 2) void k_attn(const unsigned short* __restrict__ Qp,
                                                 const unsigned short* __restrict__ Kp,
                                                 const unsigned short* __restrict__ VTp,
                                                 unsigned short* __restrict__ ctx) {
    __shared__ __align__(16) unsigned short Ks[2][64 * 128];  // [kpos][d], granule-XOR swz
    __shared__ __align__(16) unsigned short Vs[2][128 * 64];  // [d][kpos], granule-XOR swz
    const int tid = threadIdx.x, w = tid >> 6, l = tid & 63;
    const int l31 = l & 31, hi = l >> 5;
    const int x = blockIdx.x, bh = x & 31, pr = x >> 5;
    const int b = bh >> 4, h = bh & 15;
    const size_t b2048 = (size_t)b * 2048;
    const int h128 = h * 128;
    const size_t bh128 = (size_t)bh * 128;

    auto stage = [&](int kv) {
        const int bsel = kv & 1;
        const size_t kvoff = (size_t)kv * 64;
#pragma unroll
        for (int i = 0; i < 4; ++i) {
            int gi = w * 256 + i * 64 + l;          // K: 64 rows x 16 granules
            int row = gi >> 4, g = gi & 15;
            int sg = g ^ (row & 7);
            const unsigned short* src = Kp + (b2048 + kvoff + row) * 2048 + h128 + sg * 8;
            __builtin_amdgcn_global_load_lds((const void*)src,
                                             (void*)&Ks[bsel][w * 2048 + i * 512], 16, 0, 0);
        }
#pragma unroll
        for (int i = 0; i < 4; ++i) {
            int gi = w * 256 + i * 64 + l;          // V: 128 rows x 8 granules
            int row = gi >> 3, g = gi & 7;
            int sg = g ^ (row & 7);
            const unsigned short* src = VTp + (bh128 + row) * 2048 + kvoff + sg * 8;
            __builtin_amdgcn_global_load_lds((const void*)src,
                                             (void*)&Vs[bsel][w * 2048 + i * 512], 16, 0, 0);
        }
    };

    for (int pi = 0; pi < 2; ++pi) {
        const int t = pi ? pr : (15 - pr);   // paired tiles: equal total work (34 iters)
        const int q0 = t * 128;
        const int wrow0 = q0 + w * 32;
        const int qg = wrow0 + l31;          // this lane's q row

        // Q in registers: B-frag layout, q = l31, d = ds*16 + hi*8 + j
        bf16x8 qf[8];
        {
            const unsigned short* qb = Qp + (b2048 + qg) * 2048 + h128 + hi * 8;
#pragma unroll
            for (int ds = 0; ds < 8; ++ds) qf[ds] = *(const bf16x8*)(qb + ds * 16);
#pragma unroll
            for (int ds = 0; ds < 8; ++ds) asm volatile("" ::"v"(qf[ds]));
        }
        f32x16 Oa[4] = {};
        float m2 = -1e30f, l2 = 0.f;
        const int kvmax = 2 * t + 1;

        stage(0);
        for (int kv = 0; kv <= kvmax; ++kv) {
            const int cur = kv & 1;
            if (kv < kvmax) {
                stage(kv + 1);
                asm volatile("s_waitcnt vmcnt(8)" ::: "memory");
            } else {
                asm volatile("s_waitcnt vmcnt(0)" ::: "memory");
            }
            __builtin_amdgcn_s_barrier();
            __builtin_amdgcn_sched_barrier(0);

            const int kvb = kv * 64;
            if (kvb <= wrow0 + 31) {  // wave has unmasked rows
                // S[kpos][q] = K·Q^T : A = K rows, B = Q
                f32x16 S[2] = {};
                __builtin_amdgcn_s_setprio(1);
#pragma unroll
                for (int ds = 0; ds < 8; ++ds)
#pragma unroll
                    for (int st = 0; st < 2; ++st) {
                        int row = st * 32 + l31;
                        int g = (ds * 2 + hi) ^ (row & 7);
                        bf16x8 kf = *(const bf16x8*)&Ks[cur][row * 128 + g * 8];
                        S[st] = __builtin_amdgcn_mfma_f32_32x32x16_bf16(kf, qf[ds], S[st], 0, 0, 0);
                    }
                __builtin_amdgcn_s_setprio(0);

                if (kvb + 63 > wrow0) {  // diagonal: elementwise causal mask
#pragma unroll
                    for (int st = 0; st < 2; ++st)
#pragma unroll
                        for (int r = 0; r < 16; ++r) {
                            int kpos = kvb + st * 32 + (r & 3) + 8 * (r >> 2) + 4 * hi;
                            if (kpos > qg) S[st][r] = -1e30f;
                        }
                }

                // in-lane softmax (lane owns one P-row; l^32 partner shares q)
                float pmax = -1e30f;
#pragma unroll
                for (int st = 0; st < 2; ++st)
#pragma unroll
                    for (int r = 0; r < 16; ++r) pmax = fmaxf(pmax, S[st][r]);
                pmax = fmaxf(pmax, __shfl_xor(pmax, 32));
                if (__any(pmax > m2 + 8.0f)) {  // defer-max (T13)
                    float mn = fmaxf(m2, pmax);
                    float sc = __builtin_amdgcn_exp2f(m2 - mn);
                    m2 = mn;
                    l2 *= sc;
#pragma unroll
                    for (int dt = 0; dt < 4; ++dt)
#pragma unroll
                        for (int e = 0; e < 16; ++e) Oa[dt][e] *= sc;
                }
                float rs = 0.f;
#pragma unroll
                for (int st = 0; st < 2; ++st)
#pragma unroll
                    for (int r = 0; r < 16; ++r) {
                        float p = __builtin_amdgcn_exp2f(S[st][r] - m2);
                        S[st][r] = p;
                        rs += p;
                    }
                rs += __shfl_xor(rs, 32);
                l2 += rs;

                // repack P -> B-frags via hw cvt_pk (k = hi*8+j per 16-kpos step)
                bf16x8 pfrag[4];
#pragma unroll
                for (int ks = 0; ks < 4; ++ks) {
                    const int st = ks >> 1, base = (ks & 1) * 8;
                    unsigned int x0 = cvtpk(S[st][base + 0], S[st][base + 1]);
                    unsigned int x1 = cvtpk(S[st][base + 2], S[st][base + 3]);
                    unsigned int y0 = cvtpk(S[st][base + 4], S[st][base + 5]);
                    unsigned int y1 = cvtpk(S[st][base + 6], S[st][base + 7]);
                    unsigned int t0 = hi ? x0 : y0, t1 = hi ? x1 : y1;
                    t0 = (unsigned int)__shfl_xor((int)t0, 32);
                    t1 = (unsigned int)__shfl_xor((int)t1, 32);
                    u32x4 fw;
                    fw.x = hi ? t0 : x0;
                    fw.y = hi ? t1 : x1;
                    fw.z = hi ? y0 : t0;
                    fw.w = hi ? y1 : t1;
                    pfrag[ks] = __builtin_bit_cast(bf16x8, fw);
                }

                // O[d][q] += Vt·P : A = Vt rows, B = P
                __builtin_amdgcn_s_setprio(1);
#pragma unroll
                for (int ks = 0; ks < 4; ++ks)
#pragma unroll
                    for (int dt = 0; dt < 4; ++dt) {
                        int row = dt * 32 + l31;
                        int g = (ks * 2 + hi) ^ (row & 7);
                        bf16x8 vf = *(const bf16x8*)&Vs[cur][row * 64 + g * 8];
                        Oa[dt] = __builtin_amdgcn_mfma_f32_32x32x16_bf16(vf, pfrag[ks], Oa[dt], 0, 0, 0);
                    }
                __builtin_amdgcn_s_setprio(0);
            }
            __builtin_amdgcn_sched_barrier(0);
            __builtin_amdgcn_s_barrier();
        }

        // epilogue: d = dt*32 + (r&3) + 8*(r>>2) + 4*hi -> 8B packed stores
        float inv = 1.0f / l2;
        unsigned short* cb = ctx + (b2048 + qg) * 2048 + h128;
#pragma unroll
        for (int dt = 0; dt < 4; ++dt)
#pragma unroll
            for (int g = 0; g < 4; ++g) {
                uint2 pv;
                pv.x = cvtpk(Oa[dt][4 * g + 0] * inv, Oa[dt][4 * g + 1] * inv);
                pv.y = cvtpk(Oa[dt][4 * g + 2] * inv, Oa[dt][4 * g + 3] * inv);
                *(uint2*)(cb + dt * 32 + 8 * g + 4 * hi) = pv;
            }
    }
}

// ---------------- launch ----------------

extern "C" void kernel_launch(void* const* d_in, const int* in_sizes, int n_in,
                              void* d_out, int out_size, void* d_ws, size_t ws_size,
                              hipStream_t stream) {
    const float* x  = (const float*)d_in[0];
    const float* wq = (const float*)d_in[1];
    const float* wk = (const float*)d_in[2];
    const float* wv = (const float*)d_in[3];
    const float* wo = (const float*)d_in[4];

    char* ws = (char*)d_ws;
    unsigned short* xb  = (unsigned short*)(ws);                 // 16,777,216 B (reused as ctx)
    unsigned short* wT  = (unsigned short*)(ws + 16777216);      // 33,554,432 B [4][2048][2048]
    unsigned short* qkv = (unsigned short*)(ws + 50331648);      // 50,331,648 B [3][4096][2048] (V third unused)
    unsigned short* vT  = (unsigned short*)(ws + 100663296);     // 16,777,216 B [2][16][128][2048]
    float2* csT = (float2*)(ws + 117440512);                     // 1,048,576 B interleaved cos/sin
    unsigned short* ctx = xb;                                    // xb dead after gemm0

    k_conv_x<<<8192, 256, 0, stream>>>(x, xb, 2097152);
    k_wT<<<dim3(64, 64, 4), 256, 0, stream>>>(wq, wk, wv, wo, wT);
    k_cs_table<<<512, 256, 0, stream>>>(csT);
    gemm_bt<0><<<dim3(48, 32), 256, 0, stream>>>(xb, wT, (void*)qkv, vT, csT, 4096, 6144, 2048);
    k_attn<<<256, 256, 0, stream>>>(qkv, qkv + 8388608, vT, ctx);
    gemm_bt<1><<<dim3(16, 32), 256, 0, stream>>>(ctx, wT + (size_t)3 * 4194304, d_out, vT, csT,
                                                 4096, 2048, 2048);
}

// Round 10
// 244.795 us; speedup vs baseline: 1.0195x; 1.0195x over previous
//
#include <hip/hip_runtime.h>
#include <hip/hip_bf16.h>

typedef __attribute__((ext_vector_type(8))) short bf16x8;
typedef __attribute__((ext_vector_type(4))) float f32x4;
typedef __attribute__((ext_vector_type(16))) float f32x16;
typedef __attribute__((ext_vector_type(4))) unsigned int u32x4;

__device__ inline unsigned short f2bf(float f) {
    unsigned int u = __builtin_bit_cast(unsigned int, f);
    u += 0x7FFFu + ((u >> 16) & 1u);
    return (unsigned short)(u >> 16);
}
__device__ inline float bf2f(unsigned short h) {
    unsigned int u = ((unsigned int)h) << 16;
    return __builtin_bit_cast(float, u);
}
// hardware packed f32->bf16 (RNE), gfx950: no builtin -> inline asm
__device__ inline unsigned int cvtpk(float lo, float hi) {
    unsigned int r;
    asm("v_cvt_pk_bf16_f32 %0, %1, %2" : "=v"(r) : "v"(lo), "v"(hi));
    return r;
}

// ---------------- conversion kernels ----------------

__global__ void k_conv_x(const float* __restrict__ in, unsigned short* __restrict__ out, int n4) {
    int i = blockIdx.x * blockDim.x + threadIdx.x;
    if (i >= n4) return;
    float4 v = ((const float4*)in)[i];
    uint2 o;
    o.x = (unsigned)f2bf(v.x) | ((unsigned)f2bf(v.y) << 16);
    o.y = (unsigned)f2bf(v.z) | ((unsigned)f2bf(v.w) << 16);
    ((uint2*)out)[i] = o;
}

// W fp32 [2048][2048] -> W^T bf16 [2048][2048]; z selects weight
__global__ void k_wT(const float* __restrict__ w0, const float* __restrict__ w1,
                     const float* __restrict__ w2, const float* __restrict__ w3,
                     unsigned short* __restrict__ out) {
    __shared__ float tile[32][33];
    int z = blockIdx.z;
    const float* W = (z == 0) ? w0 : (z == 1) ? w1 : (z == 2) ? w2 : w3;
    unsigned short* O = out + (size_t)z * 2048 * 2048;
    int n0 = blockIdx.x * 32, k0 = blockIdx.y * 32;
    int tx = threadIdx.x & 31, ty = threadIdx.x >> 5;
#pragma unroll
    for (int j = 0; j < 4; ++j)
        tile[ty + j * 8][tx] = W[(size_t)(k0 + ty + j * 8) * 2048 + n0 + tx];
    __syncthreads();
#pragma unroll
    for (int j = 0; j < 4; ++j)
        O[(size_t)(n0 + ty + j * 8) * 2048 + k0 + tx] = f2bf(tile[tx][ty + j * 8]);
}

// ---------------- GEMM: C[M][N] = A[M][K] * Bt[N][K]^T ----------------
// R3 hot loop (128x128 tile, 4 waves, 2-barrier, gload_lds w16, granule-XOR).
// Wave N-columns remapped to wn*32 + (ni&1)*16 + (ni>>1)*64 so each lane holds
// RoPE pairs (d, d+64) in (ni, ni+2).
// OUT_MODE 0 epilogue: tsel 0/1 (Q/K): RoPE with ON-THE-FLY trig (v_exp2 +
//   v_fract + v_sin/v_cos, revolutions domain) -- no table, no epilogue loads
//   (R9 finding: csT gather at block tail cost ~8MB/XCD cold fetches + delayed
//   block retirement -> -25% occupancy). Q pre-scaled by log2e/sqrt(128).
//   tsel=2 (V): fused transpose write -> vT[b,h,d,s].
// OUT_MODE 1: f32 out (colmap-aware plain write).
template <int OUT_MODE>
__global__ __launch_bounds__(256, 6) void gemm_bt(const unsigned short* __restrict__ A,
                                                  const unsigned short* __restrict__ Bt,
                                                  void* __restrict__ outp,
                                                  unsigned short* __restrict__ vtp,
                                                  int M, int N, int K) {
    __shared__ __align__(16) unsigned short As[128 * 64];
    __shared__ __align__(16) unsigned short Bs[128 * 64];
    const int tid = threadIdx.x, w = tid >> 6, l = tid & 63;
    const int m0 = blockIdx.y * 128, n0 = blockIdx.x * 128;
    const int wm = w >> 1, wn = w & 1;
    const int l15 = l & 15, lq = l >> 4;
    f32x4 acc[4][4] = {};
    const int lr = l >> 3, lg = l & 7;
    const int srcg = lg ^ lr;  // source granule (row&7 == lr since r0 % 8 == 0)

    const int nkt = K >> 6;
    for (int kt = 0; kt < nkt; ++kt) {
        if (kt) __syncthreads();
#pragma unroll
        for (int i = 0; i < 4; ++i) {
            int r0 = (w * 4 + i) * 8;
            int row = r0 + lr;
            const unsigned short* sa = A + (size_t)(m0 + row) * K + kt * 64 + srcg * 8;
            __builtin_amdgcn_global_load_lds((const void*)sa, (void*)&As[(w * 4 + i) * 512], 16, 0, 0);
            const unsigned short* sb = Bt + (size_t)(n0 + row) * K + kt * 64 + srcg * 8;
            __builtin_amdgcn_global_load_lds((const void*)sb, (void*)&Bs[(w * 4 + i) * 512], 16, 0, 0);
        }
        __syncthreads();
#pragma unroll
        for (int kb = 0; kb < 2; ++kb) {
            bf16x8 af[4], bfr[4];
#pragma unroll
            for (int mi = 0; mi < 4; ++mi) {
                int row = wm * 64 + mi * 16 + l15;
                int g = (kb * 4 + lq) ^ (row & 7);
                af[mi] = *(const bf16x8*)&As[row * 64 + g * 8];
            }
#pragma unroll
            for (int ni = 0; ni < 4; ++ni) {
                int row = wn * 32 + (ni & 1) * 16 + (ni >> 1) * 64 + l15;  // colmap
                int g = (kb * 4 + lq) ^ (row & 7);
                bfr[ni] = *(const bf16x8*)&Bs[row * 64 + g * 8];
            }
#pragma unroll
            for (int mi = 0; mi < 4; ++mi)
#pragma unroll
                for (int ni = 0; ni < 4; ++ni)
                    acc[mi][ni] = __builtin_amdgcn_mfma_f32_16x16x32_bf16(af[mi], bfr[ni],
                                                                          acc[mi][ni], 0, 0, 0);
        }
    }
    __builtin_amdgcn_sched_barrier(0);  // keep epilogue out of the K-loop

    if constexpr (OUT_MODE == 0) {
        const int tsel = n0 >> 11, nloc = n0 & 2047;
        if (tsel < 2) {
            // Q/K: RoPE in-register, trig on the fly (no memory traffic).
            unsigned short* op = (unsigned short*)outp + (size_t)tsel * M * 2048;
            const float scale = (tsel == 0) ? 0.12751742f : 1.0f;  // log2e/sqrt(128)
#pragma unroll
            for (int ni = 0; ni < 2; ++ni) {
                const int i = wn * 32 + ni * 16 + l15;  // d in [0,64)
                // rev_freq = 10000^(-i/64) / (2*pi)
                //          = exp2(-i*log2(10000)/64 - log2(2*pi))
                const float rf =
                    __builtin_amdgcn_exp2f(-(float)i * 0.20762051f - 2.6514961f);
#pragma unroll
                for (int mi = 0; mi < 4; ++mi)
#pragma unroll
                    for (int r = 0; r < 4; ++r) {
                        int row = m0 + wm * 64 + mi * 16 + lq * 4 + r;
                        int sp = row & 2047;
                        float rev = __builtin_amdgcn_fractf((float)sp * rf);
                        float cs = __builtin_amdgcn_cosf(rev);   // cos(2*pi*rev)
                        float sn = __builtin_amdgcn_sinf(rev);   // sin(2*pi*rev)
                        float a = acc[mi][ni][r], bb = acc[mi][ni + 2][r];
                        op[(size_t)row * 2048 + nloc + i]      = f2bf((a * cs - bb * sn) * scale);
                        op[(size_t)row * 2048 + nloc + i + 64] = f2bf((bb * cs + a * sn) * scale);
                    }
            }
        } else {
            // V: fused transpose -> vT[(b*16+h)*128 + d][s], packed 8B along s
            const int h = nloc >> 7;
            const int bsel = m0 >> 11;
            const int sp0 = (m0 & 2047) + wm * 64;
#pragma unroll
            for (int mi = 0; mi < 4; ++mi)
#pragma unroll
                for (int ni = 0; ni < 4; ++ni) {
                    int d = wn * 32 + (ni & 1) * 16 + (ni >> 1) * 64 + l15;
                    uint2 pv;
                    pv.x = cvtpk(acc[mi][ni][0], acc[mi][ni][1]);
                    pv.y = cvtpk(acc[mi][ni][2], acc[mi][ni][3]);
                    *(uint2*)&vtp[((size_t)((bsel * 16 + h) * 128 + d)) * 2048 + sp0 + mi * 16 + lq * 4] = pv;
                }
        }
    } else {
        float* op = (float*)outp;
#pragma unroll
        for (int mi = 0; mi < 4; ++mi)
#pragma unroll
            for (int ni = 0; ni < 4; ++ni)
#pragma unroll
                for (int r = 0; r < 4; ++r) {
                    int row = m0 + wm * 64 + mi * 16 + lq * 4 + r;
                    int col = n0 + wn * 32 + (ni & 1) * 16 + (ni >> 1) * 64 + l15;
                    op[(size_t)row * 2048 + col] = acc[mi][ni][r];
                }
    }
}

// ---------------- flash attention (causal), v3c: swapped-QK 32x32 ----------------
// 4 waves x 32 q-rows = 128-row Q tile, paired (15-pr, pr). KV tile 64, dbuf LDS
// (64KB -> 2 blocks/CU). Softmax fully in-lane; P repack via hw cvt_pk +
// 2x shfl_xor(32) per k-step. Q pre-scaled by log2e/sqrt(128) -> exp2 domain.
__global__ __launch_bounds__(256, 2) void k_attn(const unsigned short* __restrict__ Qp,
                                                 const unsigned short* __restrict__ Kp,
                                                 const unsigned short* __restrict__ VTp,
                                                 unsigned short* __restrict__ ctx) {
    __shared__ __align__(16) unsigned short Ks[2][64 * 128];  // [kpos][d], granule-XOR swz
    __shared__ __align__(16) unsigned short Vs[2][128 * 64];  // [d][kpos], granule-XOR swz
    const int tid = threadIdx.x, w = tid >> 6, l = tid & 63;
    const int l31 = l & 31, hi = l >> 5;
    const int x = blockIdx.x, bh = x & 31, pr = x >> 5;
    const int b = bh >> 4, h = bh & 15;
    const size_t b2048 = (size_t)b * 2048;
    const int h128 = h * 128;
    const size_t bh128 = (size_t)bh * 128;

    auto stage = [&](int kv) {
        const int bsel = kv & 1;
        const size_t kvoff = (size_t)kv * 64;
#pragma unroll
        for (int i = 0; i < 4; ++i) {
            int gi = w * 256 + i * 64 + l;          // K: 64 rows x 16 granules
            int row = gi >> 4, g = gi & 15;
            int sg = g ^ (row & 7);
            const unsigned short* src = Kp + (b2048 + kvoff + row) * 2048 + h128 + sg * 8;
            __builtin_amdgcn_global_load_lds((const void*)src,
                                             (void*)&Ks[bsel][w * 2048 + i * 512], 16, 0, 0);
        }
#pragma unroll
        for (int i = 0; i < 4; ++i) {
            int gi = w * 256 + i * 64 + l;          // V: 128 rows x 8 granules
            int row = gi >> 3, g = gi & 7;
            int sg = g ^ (row & 7);
            const unsigned short* src = VTp + (bh128 + row) * 2048 + kvoff + sg * 8;
            __builtin_amdgcn_global_load_lds((const void*)src,
                                             (void*)&Vs[bsel][w * 2048 + i * 512], 16, 0, 0);
        }
    };

    for (int pi = 0; pi < 2; ++pi) {
        const int t = pi ? pr : (15 - pr);   // paired tiles: equal total work (34 iters)
        const int q0 = t * 128;
        const int wrow0 = q0 + w * 32;
        const int qg = wrow0 + l31;          // this lane's q row

        // Q in registers: B-frag layout, q = l31, d = ds*16 + hi*8 + j
        bf16x8 qf[8];
        {
            const unsigned short* qb = Qp + (b2048 + qg) * 2048 + h128 + hi * 8;
#pragma unroll
            for (int ds = 0; ds < 8; ++ds) qf[ds] = *(const bf16x8*)(qb + ds * 16);
#pragma unroll
            for (int ds = 0; ds < 8; ++ds) asm volatile("" ::"v"(qf[ds]));
        }
        f32x16 Oa[4] = {};
        float m2 = -1e30f, l2 = 0.f;
        const int kvmax = 2 * t + 1;

        stage(0);
        for (int kv = 0; kv <= kvmax; ++kv) {
            const int cur = kv & 1;
            if (kv < kvmax) {
                stage(kv + 1);
                asm volatile("s_waitcnt vmcnt(8)" ::: "memory");
            } else {
                asm volatile("s_waitcnt vmcnt(0)" ::: "memory");
            }
            __builtin_amdgcn_s_barrier();
            __builtin_amdgcn_sched_barrier(0);

            const int kvb = kv * 64;
            if (kvb <= wrow0 + 31) {  // wave has unmasked rows
                // S[kpos][q] = K·Q^T : A = K rows, B = Q
                f32x16 S[2] = {};
                __builtin_amdgcn_s_setprio(1);
#pragma unroll
                for (int ds = 0; ds < 8; ++ds)
#pragma unroll
                    for (int st = 0; st < 2; ++st) {
                        int row = st * 32 + l31;
                        int g = (ds * 2 + hi) ^ (row & 7);
                        bf16x8 kf = *(const bf16x8*)&Ks[cur][row * 128 + g * 8];
                        S[st] = __builtin_amdgcn_mfma_f32_32x32x16_bf16(kf, qf[ds], S[st], 0, 0, 0);
                    }
                __builtin_amdgcn_s_setprio(0);

                if (kvb + 63 > wrow0) {  // diagonal: elementwise causal mask
#pragma unroll
                    for (int st = 0; st < 2; ++st)
#pragma unroll
                        for (int r = 0; r < 16; ++r) {
                            int kpos = kvb + st * 32 + (r & 3) + 8 * (r >> 2) + 4 * hi;
                            if (kpos > qg) S[st][r] = -1e30f;
                        }
                }

                // in-lane softmax (lane owns one P-row; l^32 partner shares q)
                float pmax = -1e30f;
#pragma unroll
                for (int st = 0; st < 2; ++st)
#pragma unroll
                    for (int r = 0; r < 16; ++r) pmax = fmaxf(pmax, S[st][r]);
                pmax = fmaxf(pmax, __shfl_xor(pmax, 32));
                if (__any(pmax > m2 + 8.0f)) {  // defer-max (T13)
                    float mn = fmaxf(m2, pmax);
                    float sc = __builtin_amdgcn_exp2f(m2 - mn);
                    m2 = mn;
                    l2 *= sc;
#pragma unroll
                    for (int dt = 0; dt < 4; ++dt)
#pragma unroll
                        for (int e = 0; e < 16; ++e) Oa[dt][e] *= sc;
                }
                float rs = 0.f;
#pragma unroll
                for (int st = 0; st < 2; ++st)
#pragma unroll
                    for (int r = 0; r < 16; ++r) {
                        float p = __builtin_amdgcn_exp2f(S[st][r] - m2);
                        S[st][r] = p;
                        rs += p;
                    }
                rs += __shfl_xor(rs, 32);
                l2 += rs;

                // repack P -> B-frags via hw cvt_pk (k = hi*8+j per 16-kpos step)
                bf16x8 pfrag[4];
#pragma unroll
                for (int ks = 0; ks < 4; ++ks) {
                    const int st = ks >> 1, base = (ks & 1) * 8;
                    unsigned int x0 = cvtpk(S[st][base + 0], S[st][base + 1]);
                    unsigned int x1 = cvtpk(S[st][base + 2], S[st][base + 3]);
                    unsigned int y0 = cvtpk(S[st][base + 4], S[st][base + 5]);
                    unsigned int y1 = cvtpk(S[st][base + 6], S[st][base + 7]);
                    unsigned int t0 = hi ? x0 : y0, t1 = hi ? x1 : y1;
                    t0 = (unsigned int)__shfl_xor((int)t0, 32);
                    t1 = (unsigned int)__shfl_xor((int)t1, 32);
                    u32x4 fw;
                    fw.x = hi ? t0 : x0;
                    fw.y = hi ? t1 : x1;
                    fw.z = hi ? y0 : t0;
                    fw.w = hi ? y1 : t1;
                    pfrag[ks] = __builtin_bit_cast(bf16x8, fw);
                }

                // O[d][q] += Vt·P : A = Vt rows, B = P
                __builtin_amdgcn_s_setprio(1);
#pragma unroll
                for (int ks = 0; ks < 4; ++ks)
#pragma unroll
                    for (int dt = 0; dt < 4; ++dt) {
                        int row = dt * 32 + l31;
                        int g = (ks * 2 + hi) ^ (row & 7);
                        bf16x8 vf = *(const bf16x8*)&Vs[cur][row * 64 + g * 8];
                        Oa[dt] = __builtin_amdgcn_mfma_f32_32x32x16_bf16(vf, pfrag[ks], Oa[dt], 0, 0, 0);
                    }
                __builtin_amdgcn_s_setprio(0);
            }
            __builtin_amdgcn_sched_barrier(0);
            __builtin_amdgcn_s_barrier();
        }

        // epilogue: d = dt*32 + (r&3) + 8*(r>>2) + 4*hi -> 8B packed stores
        float inv = 1.0f / l2;
        unsigned short* cb = ctx + (b2048 + qg) * 2048 + h128;
#pragma unroll
        for (int dt = 0; dt < 4; ++dt)
#pragma unroll
            for (int g = 0; g < 4; ++g) {
                uint2 pv;
                pv.x = cvtpk(Oa[dt][4 * g + 0] * inv, Oa[dt][4 * g + 1] * inv);
                pv.y = cvtpk(Oa[dt][4 * g + 2] * inv, Oa[dt][4 * g + 3] * inv);
                *(uint2*)(cb + dt * 32 + 8 * g + 4 * hi) = pv;
            }
    }
}

// ---------------- launch ----------------

extern "C" void kernel_launch(void* const* d_in, const int* in_sizes, int n_in,
                              void* d_out, int out_size, void* d_ws, size_t ws_size,
                              hipStream_t stream) {
    const float* x  = (const float*)d_in[0];
    const float* wq = (const float*)d_in[1];
    const float* wk = (const float*)d_in[2];
    const float* wv = (const float*)d_in[3];
    const float* wo = (const float*)d_in[4];

    char* ws = (char*)d_ws;
    unsigned short* xb  = (unsigned short*)(ws);                 // 16,777,216 B (reused as ctx)
    unsigned short* wT  = (unsigned short*)(ws + 16777216);      // 33,554,432 B [4][2048][2048]
    unsigned short* qkv = (unsigned short*)(ws + 50331648);      // 50,331,648 B [3][4096][2048] (V third unused)
    unsigned short* vT  = (unsigned short*)(ws + 100663296);     // 16,777,216 B [2][16][128][2048]
    unsigned short* ctx = xb;                                    // xb dead after gemm0

    k_conv_x<<<8192, 256, 0, stream>>>(x, xb, 2097152);
    k_wT<<<dim3(64, 64, 4), 256, 0, stream>>>(wq, wk, wv, wo, wT);
    gemm_bt<0><<<dim3(48, 32), 256, 0, stream>>>(xb, wT, (void*)qkv, vT, 4096, 6144, 2048);
    k_attn<<<256, 256, 0, stream>>>(qkv, qkv + 8388608, vT, ctx);
    gemm_bt<1><<<dim3(16, 32), 256, 0, stream>>>(ctx, wT + (size_t)3 * 4194304, d_out, vT,
                                                 4096, 2048, 2048);
}

// Round 11
// 240.418 us; speedup vs baseline: 1.0380x; 1.0182x over previous
//
#include <hip/hip_runtime.h>
#include <hip/hip_bf16.h>

typedef __attribute__((ext_vector_type(8))) short bf16x8;
typedef __attribute__((ext_vector_type(4))) float f32x4;
typedef __attribute__((ext_vector_type(16))) float f32x16;
typedef __attribute__((ext_vector_type(4))) unsigned int u32x4;

__device__ inline unsigned short f2bf(float f) {
    unsigned int u = __builtin_bit_cast(unsigned int, f);
    u += 0x7FFFu + ((u >> 16) & 1u);
    return (unsigned short)(u >> 16);
}
__device__ inline float bf2f(unsigned short h) {
    unsigned int u = ((unsigned int)h) << 16;
    return __builtin_bit_cast(float, u);
}
// hardware packed f32->bf16 (RNE), gfx950: no builtin -> inline asm
__device__ inline unsigned int cvtpk(float lo, float hi) {
    unsigned int r;
    asm("v_cvt_pk_bf16_f32 %0, %1, %2" : "=v"(r) : "v"(lo), "v"(hi));
    return r;
}

// ---------------- conversion kernels ----------------

__global__ void k_conv_x(const float* __restrict__ in, unsigned short* __restrict__ out, int n4) {
    int i = blockIdx.x * blockDim.x + threadIdx.x;
    if (i >= n4) return;
    float4 v = ((const float4*)in)[i];
    uint2 o;
    o.x = (unsigned)f2bf(v.x) | ((unsigned)f2bf(v.y) << 16);
    o.y = (unsigned)f2bf(v.z) | ((unsigned)f2bf(v.w) << 16);
    ((uint2*)out)[i] = o;
}

// W fp32 [2048][2048] -> W^T bf16 [2048][2048]; z selects weight
__global__ void k_wT(const float* __restrict__ w0, const float* __restrict__ w1,
                     const float* __restrict__ w2, const float* __restrict__ w3,
                     unsigned short* __restrict__ out) {
    __shared__ float tile[32][33];
    int z = blockIdx.z;
    const float* W = (z == 0) ? w0 : (z == 1) ? w1 : (z == 2) ? w2 : w3;
    unsigned short* O = out + (size_t)z * 2048 * 2048;
    int n0 = blockIdx.x * 32, k0 = blockIdx.y * 32;
    int tx = threadIdx.x & 31, ty = threadIdx.x >> 5;
#pragma unroll
    for (int j = 0; j < 4; ++j)
        tile[ty + j * 8][tx] = W[(size_t)(k0 + ty + j * 8) * 2048 + n0 + tx];
    __syncthreads();
#pragma unroll
    for (int j = 0; j < 4; ++j)
        O[(size_t)(n0 + ty + j * 8) * 2048 + k0 + tx] = f2bf(tile[tx][ty + j * 8]);
}

// ---------------- GEMM: C[M][N] = A[M][K] * Bt[N][K]^T ----------------
// R3 hot loop (128x128 tile, 4 waves, 2-barrier, gload_lds w16, granule-XOR).
// Wave N-columns remapped to wn*32 + (ni&1)*16 + (ni>>1)*64 so each lane holds
// RoPE pairs (d, d+64) in (ni, ni+2).
// OUT_MODE 0 epilogue: tsel 0/1 (Q/K): RoPE with on-the-fly trig (no table
//   fetches -- R9 confirmed csT gather inflated FETCH by ~9MB). Q pre-scaled by
//   log2e/sqrt(128). tsel=2 (V): fused transpose write -> vT[b,h,d,s].
// OUT_MODE 1: f32 out (colmap-aware plain write).
template <int OUT_MODE>
__global__ __launch_bounds__(256, 6) void gemm_bt(const unsigned short* __restrict__ A,
                                                  const unsigned short* __restrict__ Bt,
                                                  void* __restrict__ outp,
                                                  unsigned short* __restrict__ vtp,
                                                  int M, int N, int K) {
    __shared__ __align__(16) unsigned short As[128 * 64];
    __shared__ __align__(16) unsigned short Bs[128 * 64];
    const int tid = threadIdx.x, w = tid >> 6, l = tid & 63;
    const int m0 = blockIdx.y * 128, n0 = blockIdx.x * 128;
    const int wm = w >> 1, wn = w & 1;
    const int l15 = l & 15, lq = l >> 4;
    f32x4 acc[4][4] = {};
    const int lr = l >> 3, lg = l & 7;
    const int srcg = lg ^ lr;  // source granule (row&7 == lr since r0 % 8 == 0)

    const int nkt = K >> 6;
    for (int kt = 0; kt < nkt; ++kt) {
        if (kt) __syncthreads();
#pragma unroll
        for (int i = 0; i < 4; ++i) {
            int r0 = (w * 4 + i) * 8;
            int row = r0 + lr;
            const unsigned short* sa = A + (size_t)(m0 + row) * K + kt * 64 + srcg * 8;
            __builtin_amdgcn_global_load_lds((const void*)sa, (void*)&As[(w * 4 + i) * 512], 16, 0, 0);
            const unsigned short* sb = Bt + (size_t)(n0 + row) * K + kt * 64 + srcg * 8;
            __builtin_amdgcn_global_load_lds((const void*)sb, (void*)&Bs[(w * 4 + i) * 512], 16, 0, 0);
        }
        __syncthreads();
#pragma unroll
        for (int kb = 0; kb < 2; ++kb) {
            bf16x8 af[4], bfr[4];
#pragma unroll
            for (int mi = 0; mi < 4; ++mi) {
                int row = wm * 64 + mi * 16 + l15;
                int g = (kb * 4 + lq) ^ (row & 7);
                af[mi] = *(const bf16x8*)&As[row * 64 + g * 8];
            }
#pragma unroll
            for (int ni = 0; ni < 4; ++ni) {
                int row = wn * 32 + (ni & 1) * 16 + (ni >> 1) * 64 + l15;  // colmap
                int g = (kb * 4 + lq) ^ (row & 7);
                bfr[ni] = *(const bf16x8*)&Bs[row * 64 + g * 8];
            }
#pragma unroll
            for (int mi = 0; mi < 4; ++mi)
#pragma unroll
                for (int ni = 0; ni < 4; ++ni)
                    acc[mi][ni] = __builtin_amdgcn_mfma_f32_16x16x32_bf16(af[mi], bfr[ni],
                                                                          acc[mi][ni], 0, 0, 0);
        }
    }
    __builtin_amdgcn_sched_barrier(0);  // keep epilogue out of the K-loop

    if constexpr (OUT_MODE == 0) {
        const int tsel = n0 >> 11, nloc = n0 & 2047;
        if (tsel < 2) {
            // Q/K: RoPE in-register, trig on the fly (no memory traffic).
            unsigned short* op = (unsigned short*)outp + (size_t)tsel * M * 2048;
            const float scale = (tsel == 0) ? 0.12751742f : 1.0f;  // log2e/sqrt(128)
#pragma unroll
            for (int ni = 0; ni < 2; ++ni) {
                const int i = wn * 32 + ni * 16 + l15;  // d in [0,64)
                // rev_freq = 10000^(-i/64) / (2*pi)
                const float rf =
                    __builtin_amdgcn_exp2f(-(float)i * 0.20762051f - 2.6514961f);
#pragma unroll
                for (int mi = 0; mi < 4; ++mi)
#pragma unroll
                    for (int r = 0; r < 4; ++r) {
                        int row = m0 + wm * 64 + mi * 16 + lq * 4 + r;
                        int sp = row & 2047;
                        float rev = __builtin_amdgcn_fractf((float)sp * rf);
                        float cs = __builtin_amdgcn_cosf(rev);   // cos(2*pi*rev)
                        float sn = __builtin_amdgcn_sinf(rev);   // sin(2*pi*rev)
                        float a = acc[mi][ni][r], bb = acc[mi][ni + 2][r];
                        op[(size_t)row * 2048 + nloc + i]      = f2bf((a * cs - bb * sn) * scale);
                        op[(size_t)row * 2048 + nloc + i + 64] = f2bf((bb * cs + a * sn) * scale);
                    }
            }
        } else {
            // V: fused transpose -> vT[(b*16+h)*128 + d][s], packed 8B along s
            const int h = nloc >> 7;
            const int bsel = m0 >> 11;
            const int sp0 = (m0 & 2047) + wm * 64;
#pragma unroll
            for (int mi = 0; mi < 4; ++mi)
#pragma unroll
                for (int ni = 0; ni < 4; ++ni) {
                    int d = wn * 32 + (ni & 1) * 16 + (ni >> 1) * 64 + l15;
                    uint2 pv;
                    pv.x = cvtpk(acc[mi][ni][0], acc[mi][ni][1]);
                    pv.y = cvtpk(acc[mi][ni][2], acc[mi][ni][3]);
                    *(uint2*)&vtp[((size_t)((bsel * 16 + h) * 128 + d)) * 2048 + sp0 + mi * 16 + lq * 4] = pv;
                }
        }
    } else {
        float* op = (float*)outp;
#pragma unroll
        for (int mi = 0; mi < 4; ++mi)
#pragma unroll
            for (int ni = 0; ni < 4; ++ni)
#pragma unroll
                for (int r = 0; r < 4; ++r) {
                    int row = m0 + wm * 64 + mi * 16 + lq * 4 + r;
                    int col = n0 + wn * 32 + (ni & 1) * 16 + (ni >> 1) * 64 + l15;
                    op[(size_t)row * 2048 + col] = acc[mi][ni][r];
                }
    }
}

// ---------------- flash attention (causal), v4: 1 tile/block, 512 blocks ----
// R10 finding: grid=256 was 1 block/CU -> pure 4-wave lockstep, no cross-block
// overlap. v4: one 128-row q-tile per block, grid 512 = 2 blocks/CU; LPT order
// (t = 15 - x>>5: 32-iter tiles dispatch first, small tiles backfill) gives
// near-perfect greedy balance (total 8704 iters / 256 CU = 34 avg = old paired
// makespan) PLUS MFMA<->VALU overlap between co-resident blocks (m114).
// Inner loop identical to v3c.
__global__ __launch_bounds__(256, 2) void k_attn(const unsigned short* __restrict__ Qp,
                                                 const unsigned short* __restrict__ Kp,
                                                 const unsigned short* __restrict__ VTp,
                                                 unsigned short* __restrict__ ctx) {
    __shared__ __align__(16) unsigned short Ks[2][64 * 128];  // [kpos][d], granule-XOR swz
    __shared__ __align__(16) unsigned short Vs[2][128 * 64];  // [d][kpos], granule-XOR swz
    const int tid = threadIdx.x, w = tid >> 6, l = tid & 63;
    const int l31 = l & 31, hi = l >> 5;
    const int x = blockIdx.x, bh = x & 31;
    const int t = 15 - (x >> 5);         // LPT: biggest tiles first
    const int b = bh >> 4, h = bh & 15;
    const size_t b2048 = (size_t)b * 2048;
    const int h128 = h * 128;
    const size_t bh128 = (size_t)bh * 128;

    auto stage = [&](int kv) {
        const int bsel = kv & 1;
        const size_t kvoff = (size_t)kv * 64;
#pragma unroll
        for (int i = 0; i < 4; ++i) {
            int gi = w * 256 + i * 64 + l;          // K: 64 rows x 16 granules
            int row = gi >> 4, g = gi & 15;
            int sg = g ^ (row & 7);
            const unsigned short* src = Kp + (b2048 + kvoff + row) * 2048 + h128 + sg * 8;
            __builtin_amdgcn_global_load_lds((const void*)src,
                                             (void*)&Ks[bsel][w * 2048 + i * 512], 16, 0, 0);
        }
#pragma unroll
        for (int i = 0; i < 4; ++i) {
            int gi = w * 256 + i * 64 + l;          // V: 128 rows x 8 granules
            int row = gi >> 3, g = gi & 7;
            int sg = g ^ (row & 7);
            const unsigned short* src = VTp + (bh128 + row) * 2048 + kvoff + sg * 8;
            __builtin_amdgcn_global_load_lds((const void*)src,
                                             (void*)&Vs[bsel][w * 2048 + i * 512], 16, 0, 0);
        }
    };

    const int q0 = t * 128;
    const int wrow0 = q0 + w * 32;
    const int qg = wrow0 + l31;          // this lane's q row

    // Q in registers: B-frag layout, q = l31, d = ds*16 + hi*8 + j
    bf16x8 qf[8];
    {
        const unsigned short* qb = Qp + (b2048 + qg) * 2048 + h128 + hi * 8;
#pragma unroll
        for (int ds = 0; ds < 8; ++ds) qf[ds] = *(const bf16x8*)(qb + ds * 16);
#pragma unroll
        for (int ds = 0; ds < 8; ++ds) asm volatile("" ::"v"(qf[ds]));
    }
    f32x16 Oa[4] = {};
    float m2 = -1e30f, l2 = 0.f;
    const int kvmax = 2 * t + 1;

    stage(0);
    for (int kv = 0; kv <= kvmax; ++kv) {
        const int cur = kv & 1;
        if (kv < kvmax) {
            stage(kv + 1);
            asm volatile("s_waitcnt vmcnt(8)" ::: "memory");
        } else {
            asm volatile("s_waitcnt vmcnt(0)" ::: "memory");
        }
        __builtin_amdgcn_s_barrier();
        __builtin_amdgcn_sched_barrier(0);

        const int kvb = kv * 64;
        if (kvb <= wrow0 + 31) {  // wave has unmasked rows
            // S[kpos][q] = K·Q^T : A = K rows, B = Q
            f32x16 S[2] = {};
            __builtin_amdgcn_s_setprio(1);
#pragma unroll
            for (int ds = 0; ds < 8; ++ds)
#pragma unroll
                for (int st = 0; st < 2; ++st) {
                    int row = st * 32 + l31;
                    int g = (ds * 2 + hi) ^ (row & 7);
                    bf16x8 kf = *(const bf16x8*)&Ks[cur][row * 128 + g * 8];
                    S[st] = __builtin_amdgcn_mfma_f32_32x32x16_bf16(kf, qf[ds], S[st], 0, 0, 0);
                }
            __builtin_amdgcn_s_setprio(0);

            if (kvb + 63 > wrow0) {  // diagonal: elementwise causal mask
#pragma unroll
                for (int st = 0; st < 2; ++st)
#pragma unroll
                    for (int r = 0; r < 16; ++r) {
                        int kpos = kvb + st * 32 + (r & 3) + 8 * (r >> 2) + 4 * hi;
                        if (kpos > qg) S[st][r] = -1e30f;
                    }
            }

            // in-lane softmax (lane owns one P-row; l^32 partner shares q)
            float pmax = -1e30f;
#pragma unroll
            for (int st = 0; st < 2; ++st)
#pragma unroll
                for (int r = 0; r < 16; ++r) pmax = fmaxf(pmax, S[st][r]);
            pmax = fmaxf(pmax, __shfl_xor(pmax, 32));
            if (__any(pmax > m2 + 8.0f)) {  // defer-max (T13)
                float mn = fmaxf(m2, pmax);
                float sc = __builtin_amdgcn_exp2f(m2 - mn);
                m2 = mn;
                l2 *= sc;
#pragma unroll
                for (int dt = 0; dt < 4; ++dt)
#pragma unroll
                    for (int e = 0; e < 16; ++e) Oa[dt][e] *= sc;
            }
            float rs = 0.f;
#pragma unroll
            for (int st = 0; st < 2; ++st)
#pragma unroll
                for (int r = 0; r < 16; ++r) {
                    float p = __builtin_amdgcn_exp2f(S[st][r] - m2);
                    S[st][r] = p;
                    rs += p;
                }
            rs += __shfl_xor(rs, 32);
            l2 += rs;

            // repack P -> B-frags via hw cvt_pk (k = hi*8+j per 16-kpos step)
            bf16x8 pfrag[4];
#pragma unroll
            for (int ks = 0; ks < 4; ++ks) {
                const int st = ks >> 1, base = (ks & 1) * 8;
                unsigned int x0 = cvtpk(S[st][base + 0], S[st][base + 1]);
                unsigned int x1 = cvtpk(S[st][base + 2], S[st][base + 3]);
                unsigned int y0 = cvtpk(S[st][base + 4], S[st][base + 5]);
                unsigned int y1 = cvtpk(S[st][base + 6], S[st][base + 7]);
                unsigned int t0 = hi ? x0 : y0, t1 = hi ? x1 : y1;
                t0 = (unsigned int)__shfl_xor((int)t0, 32);
                t1 = (unsigned int)__shfl_xor((int)t1, 32);
                u32x4 fw;
                fw.x = hi ? t0 : x0;
                fw.y = hi ? t1 : x1;
                fw.z = hi ? y0 : t0;
                fw.w = hi ? y1 : t1;
                pfrag[ks] = __builtin_bit_cast(bf16x8, fw);
            }

            // O[d][q] += Vt·P : A = Vt rows, B = P
            __builtin_amdgcn_s_setprio(1);
#pragma unroll
            for (int ks = 0; ks < 4; ++ks)
#pragma unroll
                for (int dt = 0; dt < 4; ++dt) {
                    int row = dt * 32 + l31;
                    int g = (ks * 2 + hi) ^ (row & 7);
                    bf16x8 vf = *(const bf16x8*)&Vs[cur][row * 64 + g * 8];
                    Oa[dt] = __builtin_amdgcn_mfma_f32_32x32x16_bf16(vf, pfrag[ks], Oa[dt], 0, 0, 0);
                }
            __builtin_amdgcn_s_setprio(0);
        }
        __builtin_amdgcn_sched_barrier(0);
        __builtin_amdgcn_s_barrier();
    }

    // epilogue: d = dt*32 + (r&3) + 8*(r>>2) + 4*hi -> 8B packed stores
    float inv = 1.0f / l2;
    unsigned short* cb = ctx + (b2048 + qg) * 2048 + h128;
#pragma unroll
    for (int dt = 0; dt < 4; ++dt)
#pragma unroll
        for (int g = 0; g < 4; ++g) {
            uint2 pv;
            pv.x = cvtpk(Oa[dt][4 * g + 0] * inv, Oa[dt][4 * g + 1] * inv);
            pv.y = cvtpk(Oa[dt][4 * g + 2] * inv, Oa[dt][4 * g + 3] * inv);
            *(uint2*)(cb + dt * 32 + 8 * g + 4 * hi) = pv;
        }
}

// ---------------- launch ----------------

extern "C" void kernel_launch(void* const* d_in, const int* in_sizes, int n_in,
                              void* d_out, int out_size, void* d_ws, size_t ws_size,
                              hipStream_t stream) {
    const float* x  = (const float*)d_in[0];
    const float* wq = (const float*)d_in[1];
    const float* wk = (const float*)d_in[2];
    const float* wv = (const float*)d_in[3];
    const float* wo = (const float*)d_in[4];

    char* ws = (char*)d_ws;
    unsigned short* xb  = (unsigned short*)(ws);                 // 16,777,216 B (reused as ctx)
    unsigned short* wT  = (unsigned short*)(ws + 16777216);      // 33,554,432 B [4][2048][2048]
    unsigned short* qkv = (unsigned short*)(ws + 50331648);      // 50,331,648 B [3][4096][2048] (V third unused)
    unsigned short* vT  = (unsigned short*)(ws + 100663296);     // 16,777,216 B [2][16][128][2048]
    unsigned short* ctx = xb;                                    // xb dead after gemm0

    k_conv_x<<<8192, 256, 0, stream>>>(x, xb, 2097152);
    k_wT<<<dim3(64, 64, 4), 256, 0, stream>>>(wq, wk, wv, wo, wT);
    gemm_bt<0><<<dim3(48, 32), 256, 0, stream>>>(xb, wT, (void*)qkv, vT, 4096, 6144, 2048);
    k_attn<<<512, 256, 0, stream>>>(qkv, qkv + 8388608, vT, ctx);
    gemm_bt<1><<<dim3(16, 32), 256, 0, stream>>>(ctx, wT + (size_t)3 * 4194304, d_out, vT,
                                                 4096, 2048, 2048);
}